// Round 1
// 100.196 us; speedup vs baseline: 1.0162x; 1.0162x over previous
//
#include <hip/hip_runtime.h>

// CLUB loss, algebraically collapsed (O(N*d), x read once):
//   out = -0.5/N * P + 0.5/N^2 * ( <Sx2,Sinv> - 2<Sx,Smuinv> + N*Smu2inv )
// Sinv[d]=sum_i e^{-lv}, Smuinv[d]=sum_i mu e^{-lv}, Sx[d]=sum_j x, Sx2[d]=sum_j x^2
// P = sum (x-mu)^2 e^{-lv},  Smu2inv = sum mu^2 e^{-lv}
//
// R6: same verified streaming structure as R5. Two changes:
//  (1) club_fin rebuilt: float4 loads (64 dwordx4/thread, unroll 16) instead of
//      128 scalar dwords/thread -> ~4x the bytes in flight against LLC latency;
//      wave-shuffle reduce instead of the 11-barrier 1024-wide double tree.
//  (2) club_main tail: the 4 independent COLREDs merged into one float4[4][256]
//      LDS reduce -> 4 barriers instead of 15.

#define Dd   512
#define HWs  784
#define Nn   6272
#define LSx  260      // LDS x-tile stride: %4==0 (b128-aligned), %32==4 -> 2-way only
#define REP  64

// ws float layout (all atomics, zeroed):
//   [a*REP*512 + r*512 + c], a: 0=Inv 1=Mu 2=Sx 3=Sx2, r in [0,64), c in [0,512)
//   -> 512 KB. Doubles at byte 524288: P[64], M2[64].

__global__ __launch_bounds__(256) void club_main(
    const float* __restrict__ x, const float* __restrict__ p_mu,
    const float* __restrict__ p_lv, float* __restrict__ ws)
{
    __shared__ __align__(16) float smem[16 * LSx + 16];

    const int t   = threadIdx.x;
    const int bid = blockIdx.x;
    const int ct  = bid & 1;
    const int ht  = (bid >> 1) % 49;
    const int b   = bid / 98;
    const int c0  = ct * 256;
    const int hw0 = ht * 16;
    const int rep = bid & (REP - 1);

    // ---- issue ALL global loads first (12 dwordx4 in flight) ----
    const int dx = t >> 2;            // 0..63 (+64k)
    const int g  = t & 3;             // hw group within tile
    const float* xb = x + ((size_t)(b * Dd + c0 + dx) * HWs + hw0 + 4 * g);
    const float4 x0 = *(const float4*)(xb);
    const float4 x1 = *(const float4*)(xb +  64 * HWs);
    const float4 x2 = *(const float4*)(xb + 128 * HWs);
    const float4 x3 = *(const float4*)(xb + 192 * HWs);

    const int r0 = b * HWs + hw0;
    const size_t mbase = (size_t)(r0 + (t >> 6)) * Dd + c0 + 4 * (t & 63);
    const float* mp = p_mu + mbase;
    const float* lp = p_lv + mbase;
    const float4 m0 = *(const float4*)(mp);
    const float4 m1 = *(const float4*)(mp + 2048);
    const float4 m2 = *(const float4*)(mp + 4096);
    const float4 m3 = *(const float4*)(mp + 6144);
    const float4 l0 = *(const float4*)(lp);
    const float4 l1 = *(const float4*)(lp + 2048);
    const float4 l2 = *(const float4*)(lp + 4096);
    const float4 l3 = *(const float4*)(lp + 6144);

    // ---- transpose x into LDS: xs[hw_row][col] ----
    {
        const int rr = 4 * g;
#define XST(V, K) do {                                                \
        const int c = dx + 64 * (K);                                  \
        smem[(rr + 0) * LSx + c] = (V).x;                             \
        smem[(rr + 1) * LSx + c] = (V).y;                             \
        smem[(rr + 2) * LSx + c] = (V).z;                             \
        smem[(rr + 3) * LSx + c] = (V).w;                             \
    } while (0)
        XST(x0, 0); XST(x1, 1); XST(x2, 2); XST(x3, 3);
#undef XST
    }
    __syncthreads();

    // ---- main compute: thread owns cols 4*(t&63), rows (t>>6)+4k ----
    float4 aI = {0,0,0,0}, aM = {0,0,0,0}, sX = {0,0,0,0}, sX2 = {0,0,0,0};
    float aP = 0.f, aM2 = 0.f;
    const int cc = 4 * (t & 63);
    const int rb = t >> 6;

#define ACC1(XV, MU, LV, F) do {                                      \
        const float iev = __expf(-(LV).F);                            \
        const float dd  = (XV).F - (MU).F;                            \
        aP += dd * dd * iev;                                          \
        aI.F += iev;                                                  \
        const float mi = (MU).F * iev;                                \
        aM.F += mi; aM2 += (MU).F * mi;                               \
        sX.F += (XV).F; sX2.F += (XV).F * (XV).F;                     \
    } while (0)
#define ACCROW(K, MU, LV) do {                                        \
        const float4 xv = *(const float4*)&smem[(rb + 4 * (K)) * LSx + cc]; \
        ACC1(xv, MU, LV, x); ACC1(xv, MU, LV, y);                     \
        ACC1(xv, MU, LV, z); ACC1(xv, MU, LV, w);                     \
    } while (0)
    ACCROW(0, m0, l0); ACCROW(1, m1, l1); ACCROW(2, m2, l2); ACCROW(3, m3, l3);
#undef ACCROW
#undef ACC1

    // ---- merged per-column LDS reduce: red4[a][i], a in 0..3, i in 0..255 ----
    // threads i, i+64, i+128, i+192 share cols 4*(i&63); fold 256 -> 64 rows.
    float4* red4 = (float4*)smem;         // [4][256] = 16 KB (x-tile dead)
    __syncthreads();                      // S1: x-tile reads done
    red4[0 * 256 + t] = aI;
    red4[1 * 256 + t] = aM;
    red4[2 * 256 + t] = sX;
    red4[3 * 256 + t] = sX2;

    // scalar wave reduce (register-only), park leaders beyond red4 region
#pragma unroll
    for (int off = 32; off > 0; off >>= 1) {
        aP  += __shfl_down(aP,  off);
        aM2 += __shfl_down(aM2, off);
    }
    if ((t & 63) == 0) {
        smem[16 * LSx + (t >> 6)]     = aP;
        smem[16 * LSx + 8 + (t >> 6)] = aM2;
    }
    __syncthreads();                      // S2

    // stage A: 512 fold-items (4 arrays x 128), 2 per thread
    {
        const int a0 = t >> 7,       i0 = t & 127;
        const int a1 = 2 + (t >> 7), i1 = t & 127;
        float4 u0 = red4[a0 * 256 + i0], v0 = red4[a0 * 256 + i0 + 128];
        float4 u1 = red4[a1 * 256 + i1], v1 = red4[a1 * 256 + i1 + 128];
        u0.x += v0.x; u0.y += v0.y; u0.z += v0.z; u0.w += v0.w;
        u1.x += v1.x; u1.y += v1.y; u1.z += v1.z; u1.w += v1.w;
        red4[a0 * 256 + i0] = u0;
        red4[a1 * 256 + i1] = u1;
    }
    __syncthreads();                      // S3

    // stage B: 256 fold-items (4 arrays x 64), 1 per thread
    {
        const int a = t >> 6, i = t & 63;
        float4 u = red4[a * 256 + i], v = red4[a * 256 + i + 64];
        u.x += v.x; u.y += v.y; u.z += v.z; u.w += v.w;
        red4[a * 256 + i] = u;
    }
    __syncthreads();                      // S4

    // ---- fire-and-forget atomics to 64-way replicated accumulators ----
    if (t < 64) {
        const float4 rI  = red4[0 * 256 + t];
        const float4 rM  = red4[1 * 256 + t];
        const float4 rX  = red4[2 * 256 + t];
        const float4 rX2 = red4[3 * 256 + t];
        const int c = c0 + 4 * t;
        float* wi = ws + (0 * REP + rep) * Dd + c;
        float* wm = ws + (1 * REP + rep) * Dd + c;
        float* wx = ws + (2 * REP + rep) * Dd + c;
        float* w2 = ws + (3 * REP + rep) * Dd + c;
        atomicAdd(wi + 0, rI.x); atomicAdd(wi + 1, rI.y);
        atomicAdd(wi + 2, rI.z); atomicAdd(wi + 3, rI.w);
        atomicAdd(wm + 0, rM.x); atomicAdd(wm + 1, rM.y);
        atomicAdd(wm + 2, rM.z); atomicAdd(wm + 3, rM.w);
        atomicAdd(wx + 0, rX.x); atomicAdd(wx + 1, rX.y);
        atomicAdd(wx + 2, rX.z); atomicAdd(wx + 3, rX.w);
        atomicAdd(w2 + 0, rX2.x); atomicAdd(w2 + 1, rX2.y);
        atomicAdd(w2 + 2, rX2.z); atomicAdd(w2 + 3, rX2.w);
    }
    if (t == 0) {
        double* wd = (double*)((char*)ws + 524288);
        atomicAdd(wd + rep, (double)(smem[16*LSx+0] + smem[16*LSx+1]
                                   + smem[16*LSx+2] + smem[16*LSx+3]));
        atomicAdd(wd + REP + rep, (double)(smem[16*LSx+8] + smem[16*LSx+9]
                                         + smem[16*LSx+10] + smem[16*LSx+11]));
    }
}

// Finalize: 512 threads, float4 loads, wave-shuffle reductions.
// thread t: f4c = t&127 (float4 column, 128 cover all 512 cols),
//           grp = t>>7 in [0,4): owns reps [grp*16, grp*16+16).
// 64 dwordx4 loads/thread in unroll-16 bursts -> ~128 KB in flight.
__global__ __launch_bounds__(512) void club_fin(
    const float* __restrict__ ws, float* __restrict__ out)
{
    __shared__ __align__(16) float4 R[4][4][128];   // [grp][a][f4c] = 32 KB
    __shared__ double dpart[2];

    const int t   = threadIdx.x;
    const int f4c = t & 127;
    const int grp = t >> 7;
    const float4* w4 = (const float4*)ws;

#pragma unroll
    for (int a = 0; a < 4; ++a) {
        float4 s = {0.f, 0.f, 0.f, 0.f};
#pragma unroll
        for (int k = 0; k < 16; ++k) {
            const float4 v = w4[(a * REP + grp * 16 + k) * 128 + f4c];
            s.x += v.x; s.y += v.y; s.z += v.z; s.w += v.w;
        }
        R[grp][a][f4c] = s;
    }
    __syncthreads();

    if (t < 128) {
        // combine 4 grp-partials in double, then per-column dot contribution
#define CMB(A, F) ((double)R[0][A][t].F + (double)R[1][A][t].F \
                 + (double)R[2][A][t].F + (double)R[3][A][t].F)
        double dc = 0.0;
#define DCC(F) do { const double sI = CMB(0, F), sM = CMB(1, F),      \
                                 sX = CMB(2, F), sX2 = CMB(3, F);     \
                    dc += sX2 * sI - 2.0 * sX * sM; } while (0)
        DCC(x); DCC(y); DCC(z); DCC(w);
#undef DCC
#undef CMB
#pragma unroll
        for (int off = 32; off > 0; off >>= 1)
            dc += __shfl_down(dc, off);
        if ((t & 63) == 0) dpart[t >> 6] = dc;
    }
    __syncthreads();

    if (t < 64) {
        const double* wd = (const double*)((const char*)ws + 524288);
        double p = wd[t], m2 = wd[REP + t];
#pragma unroll
        for (int off = 32; off > 0; off >>= 1) {
            p  += __shfl_down(p,  off);
            m2 += __shfl_down(m2, off);
        }
        if (t == 0) {
            const double sumD = dpart[0] + dpart[1] + (double)Nn * m2;
            out[0] = (float)((-0.5 / (double)Nn) * p
                           + (0.5 / ((double)Nn * (double)Nn)) * sumD);
        }
    }
}

extern "C" void kernel_launch(void* const* d_in, const int* in_sizes, int n_in,
                              void* d_out, int out_size, void* d_ws, size_t ws_size,
                              hipStream_t stream) {
    const float* x    = (const float*)d_in[0];
    const float* p_mu = (const float*)d_in[1];
    const float* p_lv = (const float*)d_in[2];
    float* ws = (float*)d_ws;

    // zero atomic accumulators: 512 KB floats + 128 doubles
    hipMemsetAsync(d_ws, 0, 524288 + 1024, stream);

    club_main<<<784, 256, 0, stream>>>(x, p_mu, p_lv, ws);
    club_fin<<<1, 512, 0, stream>>>(ws, (float*)d_out);
}